// Round 6
// baseline (6764.236 us; speedup 1.0000x reference)
//
#include <hip/hip_runtime.h>
#include <stdint.h>

#define GW 16   // workgroups per group
#define NU 32   // hidden units per WG
#define HD 512
#define SEQ 512
#define DX 40
#define MB 16   // batch rows per group

using short8 = __attribute__((ext_vector_type(8))) short;
using f32x4  = __attribute__((ext_vector_type(4))) float;
typedef unsigned long long u64;

__device__ __forceinline__ unsigned short f2bf(float f) {
  uint32_t u = __builtin_bit_cast(uint32_t, f);
  u += 0x7fffu + ((u >> 16) & 1u);
  return (unsigned short)(u >> 16);
}
__device__ __forceinline__ float sigm(float x) { return 1.0f / (1.0f + __expf(-x)); }

#define MFMA_B16(a, b, c) __builtin_amdgcn_mfma_f32_16x16x32_bf16((a), (b), (c), 0, 0, 0)

// R9: tag-in-word + wave specialization = ONE LLC round trip per step.
//  - h exchange words: 8B {lo32 = 2x bf16 h, hi32 = tag = t+1}, relaxed AGENT
//    atomics. Elementwise threads publish DIRECTLY (fire-and-forget): no
//    h_stage hop, no vmcnt drain, no flags. The tag is the publication.
//  - tile layout per (group, parity): [16 rows][256 words]; producer wg owns
//    words [wg*16, wg*16+16) of each row.
//  - comm waves 8,9 (128 thr): thread ct polls words 2ct,2ct+1 of all 16 rows
//    (32 words, ONE producer = wg ct>>3), reloads only stale, stages h_s/x_s,
//    bumps in_ready. Compute waves 0-7 never touch vmcnt.
//  - sync_s[0] cnt_gates (+8/step), sync_s[2] in_ready (+2/iter). No other sync.
//  - Overwrite safety (tag-mediated 2-deep induction): producer writes tag u+3
//    over tag u+1 words only after consuming tags u+2 from ALL WGs => all WGs
//    finished step u+1 => their comm read ALL tag u+1 words (their 128 threads
//    collectively check the entire tile). Tags observable while polling for
//    u+1 are exactly {u-1 (or 0), u+1}. Deadlock-free: tags monotone.
//  - gate_s@t+1 vs elementwise reads@t: MFMA t+1 <- in_ready 2(t+1) <- comm
//    read own tags t+1 <- own elementwise t stores (which data-depend on all
//    gate_s reads of step t). h_s/x_s parity: comm iter u overwrites buffer
//    last read by MFMA u-1; comm u <- tags u+1 <- own elementwise u <- own
//    MFMA u done (program order after MFMA u-1).

// ---------------- GRU persistent kernel ----------------
__global__ __launch_bounds__(640, 1) void gru_kernel(
    const float* __restrict__ x, const float* __restrict__ Wih,
    const float* __restrict__ Whh, const float* __restrict__ bih,
    const float* __restrict__ bhh, u64* __restrict__ hbuf,
    float* __restrict__ o1, float* __restrict__ stats)
{
  const int wg = blockIdx.x & (GW - 1);
  const int g  = blockIdx.x >> 4;
  const int tid = threadIdx.x;
  const int wave = tid >> 6;
  const int lane = tid & 63;
  const int u0 = wg * NU;
  const int bg = g * MB;

  __shared__ __align__(16) unsigned short h_s[2][MB][520];
  __shared__ __align__(16) unsigned short x_s[2][MB][72];  // 40..63 zero pad
  __shared__ float gate_s[3][MB][NU];
  __shared__ float xn_s[MB][NU];
  __shared__ uint32_t sync_s[4];

  // weight B-fragments. B[k][n]: n=lane&15, k=(lane>>4)*8+j.
  short8 bfrag[18];
  const int myGate = wave >> 1;
  const int ut = wave & 1;
  const int kq = (lane >> 4) * 8;
  if (wave < 6) {
    const int row = myGate * HD + u0 + ut * 16 + (lane & 15);
    for (int kt = 0; kt < 16; ++kt) {
      const float* p = Whh + (size_t)row * HD + kt * 32 + kq;
      short8 f;
#pragma unroll
      for (int j = 0; j < 8; ++j) f[j] = (short)f2bf(p[j]);
      bfrag[kt] = f;
    }
    for (int kt = 16; kt < 18; ++kt) {     // x cols: r,z only (n via xn MFMA)
      short8 f;
#pragma unroll
      for (int j = 0; j < 8; ++j) {
        int c = kt * 32 + kq + j - HD;
        float v = (myGate < 2 && c < DX) ? Wih[(size_t)row * DX + c] : 0.0f;
        f[j] = (short)f2bf(v);
      }
      bfrag[kt] = f;
    }
  } else if (wave < 8) {                   // waves 6,7: Wn fragments, K=64 pad
    const int row = 2 * HD + u0 + (wave - 6) * 16 + (lane & 15);
    for (int kt = 0; kt < 2; ++kt) {
      short8 f;
#pragma unroll
      for (int j = 0; j < 8; ++j) {
        int c = kt * 32 + kq + j;
        f[j] = (short)((c < DX) ? f2bf(Wih[(size_t)row * DX + c]) : 0);
      }
      bfrag[kt] = f;
    }
  }

  const int sb = tid >> 5;   // rows sb and sb+8 (elementwise, tid<256)
  const int su = tid & 31;
  float b_r = 0.f, b_z = 0.f, b_in = 0.f, b_hn = 0.f;
  if (tid < 256) {
    b_r  = bih[u0 + su] + bhh[u0 + su];
    b_z  = bih[HD + u0 + su] + bhh[HD + u0 + su];
    b_in = bih[2 * HD + u0 + su];
    b_hn = bhh[2 * HD + u0 + su];
  }

  // prologue: zero h_s (h0=0) and x_s; BARRIER; then stage x(0).
  for (int i = tid; i < 4160; i += 640) ((u64*)h_s)[i] = 0ull;
  for (int i = tid; i < 576;  i += 640) ((u64*)x_s)[i] = 0ull;
  if (tid < 4) sync_s[tid] = 0;
  __syncthreads();
  {
    int r = tid / 40, c = tid % 40;   // 640 threads == 16*40 exactly
    x_s[0][r][c] = f2bf(x[((size_t)(bg + r) * SEQ) * DX + c]);
  }
  __syncthreads();

  if (wave < 8) {
    // ================= COMPUTE =================
    float hpA = 0.f, hpB = 0.f, ssum = 0.f, ssq = 0.f;
    for (int t = 0; t < SEQ; ++t) {
      if (t) {
        while (__hip_atomic_load(&sync_s[2], __ATOMIC_ACQUIRE,
                                 __HIP_MEMORY_SCOPE_WORKGROUP) < 2u * (unsigned)t)
          __builtin_amdgcn_s_sleep(1);
      }
      const int p = t & 1;
      if (wave < 6) {
        const int m = lane & 15;
        f32x4 a0 = {0.f, 0.f, 0.f, 0.f}, a1 = {0.f, 0.f, 0.f, 0.f};
#pragma unroll
        for (int kt = 0; kt < 16; kt += 2) {
          short8 ha0 = *(const short8*)(&h_s[p][m][kt * 32 + kq]);
          short8 ha1 = *(const short8*)(&h_s[p][m][(kt + 1) * 32 + kq]);
          a0 = MFMA_B16(ha0, bfrag[kt], a0);
          a1 = MFMA_B16(ha1, bfrag[kt + 1], a1);
        }
        short8 ax0 = *(const short8*)(&x_s[p][m][kq]);
        short8 ax1 = *(const short8*)(&x_s[p][m][32 + kq]);
        a0 = MFMA_B16(ax0, bfrag[16], a0);
        a1 = MFMA_B16(ax1, bfrag[17], a1);
        f32x4 acc = a0 + a1;
#pragma unroll
        for (int r = 0; r < 4; ++r)   // C/D: col=lane&15, row=(lane>>4)*4+r
          gate_s[myGate][(lane >> 4) * 4 + r][ut * 16 + (lane & 15)] = acc[r];
      } else {
        const int m = lane & 15;
        f32x4 acc = {0.f, 0.f, 0.f, 0.f};
        short8 ax0 = *(const short8*)(&x_s[p][m][kq]);
        short8 ax1 = *(const short8*)(&x_s[p][m][32 + kq]);
        acc = MFMA_B16(ax0, bfrag[0], acc);
        acc = MFMA_B16(ax1, bfrag[1], acc);
#pragma unroll
        for (int r = 0; r < 4; ++r)
          xn_s[(lane >> 4) * 4 + r][(wave - 6) * 16 + (lane & 15)] = acc[r];
      }
      asm volatile("s_waitcnt lgkmcnt(0)" ::: "memory");
      if (lane == 0)
        __hip_atomic_fetch_add(&sync_s[0], 1u, __ATOMIC_RELAXED,
                               __HIP_MEMORY_SCOPE_WORKGROUP);
      if (tid < 256) {
        while (__hip_atomic_load(&sync_s[0], __ATOMIC_ACQUIRE,
                                 __HIP_MEMORY_SCOPE_WORKGROUP) < 8u * (unsigned)(t + 1))
          __builtin_amdgcn_s_sleep(1);
        float rA = sigm(gate_s[0][sb][su] + b_r);
        float zA = sigm(gate_s[1][sb][su] + b_z);
        float nA = tanhf(xn_s[sb][su] + b_in + rA * (gate_s[2][sb][su] + b_hn));
        float hA = (1.0f - zA) * nA + zA * hpA;
        float rB = sigm(gate_s[0][sb + 8][su] + b_r);
        float zB = sigm(gate_s[1][sb + 8][su] + b_z);
        float nB = tanhf(xn_s[sb + 8][su] + b_in + rB * (gate_s[2][sb + 8][su] + b_hn));
        float hB = (1.0f - zB) * nB + zB * hpB;
        hpA = hA; hpB = hB;
        ssum += hA + hB; ssq += hA * hA + hB * hB;
        // publish tagged words FIRST (the critical path), fire-and-forget
        float pA = __shfl_xor(hA, 1);
        float pB = __shfl_xor(hB, 1);
        if (t < SEQ - 1 && (su & 1) == 0) {
          u64 tg = ((u64)(unsigned)(t + 1)) << 32;
          u64 wA = (u64)((uint32_t)f2bf(hA) | ((uint32_t)f2bf(pA) << 16)) | tg;
          u64 wB = (u64)((uint32_t)f2bf(hB) | ((uint32_t)f2bf(pB) << 16)) | tg;
          u64* hbo = hbuf + ((size_t)g * 2 + ((t + 1) & 1)) * 4096;
          const int w = wg * 16 + (su >> 1);
          __hip_atomic_store(hbo + sb * 256 + w, wA,
                             __ATOMIC_RELAXED, __HIP_MEMORY_SCOPE_AGENT);
          __hip_atomic_store(hbo + (sb + 8) * 256 + w, wB,
                             __ATOMIC_RELAXED, __HIP_MEMORY_SCOPE_AGENT);
        }
        o1[((size_t)(bg + sb) * SEQ + t) * HD + u0 + su] = hA;
        o1[((size_t)(bg + sb + 8) * SEQ + t) * HD + u0 + su] = hB;
      }
    }
    if (tid < 256) {
      atomicAdd(&stats[u0 + su], ssum);
      atomicAdd(&stats[HD + u0 + su], ssq);
    }
  } else {
    // ================= COMM =================
    const int ct = tid - 512;             // 0..127; producer = wg ct>>3
    for (int u = 0; u < SEQ - 1; ++u) {
      const u64* hbin = hbuf + ((size_t)g * 2 + ((u + 1) & 1)) * 4096;
      // x(u+1) prefetch (latency rides under the poll)
      float xv[5];
      const int xi = ct * 5;
#pragma unroll
      for (int i = 0; i < 5; ++i) {
        int idx = xi + i, r = idx / 40, c = idx % 40;
        xv[i] = x[((size_t)(bg + r) * SEQ + (u + 1)) * DX + c];
      }
      // poll 32 tagged words (words 2ct,2ct+1 of each row), reload stale only
      u64 v0[16], v1[16];
      const int wa = 2 * ct, wb = 2 * ct + 1;
#pragma unroll
      for (int i = 0; i < 16; ++i) {
        v0[i] = __hip_atomic_load(hbin + i * 256 + wa, __ATOMIC_RELAXED,
                                  __HIP_MEMORY_SCOPE_AGENT);
        v1[i] = __hip_atomic_load(hbin + i * 256 + wb, __ATOMIC_RELAXED,
                                  __HIP_MEMORY_SCOPE_AGENT);
      }
      const unsigned tg = (unsigned)(u + 1);
      for (;;) {
        uint32_t m0 = 0, m1 = 0;
#pragma unroll
        for (int i = 0; i < 16; ++i) {
          m0 |= ((unsigned)(v0[i] >> 32) != tg) ? (1u << i) : 0u;
          m1 |= ((unsigned)(v1[i] >> 32) != tg) ? (1u << i) : 0u;
        }
        if (!(m0 | m1)) break;
        __builtin_amdgcn_s_sleep(1);
#pragma unroll
        for (int i = 0; i < 16; ++i) {
          if (m0 & (1u << i))
            v0[i] = __hip_atomic_load(hbin + i * 256 + wa, __ATOMIC_RELAXED,
                                      __HIP_MEMORY_SCOPE_AGENT);
          if (m1 & (1u << i))
            v1[i] = __hip_atomic_load(hbin + i * 256 + wb, __ATOMIC_RELAXED,
                                      __HIP_MEMORY_SCOPE_AGENT);
        }
      }
      // stage h_s/x_s for step u+1
      const int np = (u + 1) & 1;
#pragma unroll
      for (int i = 0; i < 16; ++i)
        *(u64*)(&h_s[np][i][ct * 4]) =
            (v0[i] & 0xffffffffull) | (v1[i] << 32);
#pragma unroll
      for (int i = 0; i < 5; ++i) {
        int idx = xi + i, r = idx / 40, c = idx % 40;
        x_s[np][r][c] = f2bf(xv[i]);
      }
      asm volatile("s_waitcnt lgkmcnt(0)" ::: "memory");
      if (lane == 0)
        __hip_atomic_fetch_add(&sync_s[2], 1u, __ATOMIC_RELAXED,
                               __HIP_MEMORY_SCOPE_WORKGROUP);
    }
  }
}

// ---------------- LSTM persistent kernel ----------------
__global__ __launch_bounds__(640, 1) void lstm_kernel(
    const float* __restrict__ x, const float* __restrict__ Wih,
    const float* __restrict__ Whh, const float* __restrict__ bih,
    const float* __restrict__ bhh, const float* __restrict__ ssr,
    u64* __restrict__ hbuf, float* __restrict__ o2)
{
  const int wg = blockIdx.x & (GW - 1);
  const int g  = blockIdx.x >> 4;
  const int tid = threadIdx.x;
  const int wave = tid >> 6;
  const int lane = tid & 63;
  const int u0 = wg * NU;
  const int bg = g * MB;

  __shared__ __align__(16) unsigned short h_s[2][MB][520];
  __shared__ __align__(16) unsigned short x_s[2][MB][72];  // 40 ssr, 41.. pad
  __shared__ float gate_s[4][MB][NU];
  __shared__ uint32_t sync_s[4];

  short8 bfrag[18];
  const int myGate = wave >> 1;            // 0..3 for waves 0..7
  const int ut = wave & 1;
  const int kq = (lane >> 4) * 8;
  if (wave < 8) {
    const int row = myGate * HD + u0 + ut * 16 + (lane & 15);
    for (int kt = 0; kt < 16; ++kt) {
      const float* p = Whh + (size_t)row * HD + kt * 32 + kq;
      short8 f;
#pragma unroll
      for (int j = 0; j < 8; ++j) f[j] = (short)f2bf(p[j]);
      bfrag[kt] = f;
    }
    for (int kt = 16; kt < 18; ++kt) {     // Wih has 41 cols (x, ssr)
      short8 f;
#pragma unroll
      for (int j = 0; j < 8; ++j) {
        int c = kt * 32 + kq + j - HD;
        float v = (c < 41) ? Wih[(size_t)row * 41 + c] : 0.0f;
        f[j] = (short)f2bf(v);
      }
      bfrag[kt] = f;
    }
  }

  const int sb = tid >> 5;
  const int su = tid & 31;
  float b_i = 0.f, b_f = 0.f, b_g = 0.f, b_o = 0.f;
  if (tid < 256) {
    b_i = bih[u0 + su] + bhh[u0 + su];
    b_f = bih[HD + u0 + su] + bhh[HD + u0 + su];
    b_g = bih[2 * HD + u0 + su] + bhh[2 * HD + u0 + su];
    b_o = bih[3 * HD + u0 + su] + bhh[3 * HD + u0 + su];
  }

  for (int i = tid; i < 4160; i += 640) ((u64*)h_s)[i] = 0ull;
  for (int i = tid; i < 576;  i += 640) ((u64*)x_s)[i] = 0ull;
  if (tid < 4) sync_s[tid] = 0;
  __syncthreads();
  {
    int r = tid / 40, c = tid % 40;
    x_s[0][r][c] = f2bf(x[((size_t)(bg + r) * SEQ) * DX + c]);
  }
  if (tid < 16) x_s[0][tid][40] = f2bf(ssr[(size_t)(bg + tid) * SEQ]);
  __syncthreads();

  if (wave < 8) {
    // ================= COMPUTE =================
    float cA = 0.f, cB = 0.f;
    for (int t = 0; t < SEQ; ++t) {
      if (t) {
        while (__hip_atomic_load(&sync_s[2], __ATOMIC_ACQUIRE,
                                 __HIP_MEMORY_SCOPE_WORKGROUP) < 2u * (unsigned)t)
          __builtin_amdgcn_s_sleep(1);
      }
      const int p = t & 1;
      {
        const int m = lane & 15;
        f32x4 a0 = {0.f, 0.f, 0.f, 0.f}, a1 = {0.f, 0.f, 0.f, 0.f};
#pragma unroll
        for (int kt = 0; kt < 16; kt += 2) {
          short8 ha0 = *(const short8*)(&h_s[p][m][kt * 32 + kq]);
          short8 ha1 = *(const short8*)(&h_s[p][m][(kt + 1) * 32 + kq]);
          a0 = MFMA_B16(ha0, bfrag[kt], a0);
          a1 = MFMA_B16(ha1, bfrag[kt + 1], a1);
        }
        short8 ax0 = *(const short8*)(&x_s[p][m][kq]);
        short8 ax1 = *(const short8*)(&x_s[p][m][32 + kq]);
        a0 = MFMA_B16(ax0, bfrag[16], a0);
        a1 = MFMA_B16(ax1, bfrag[17], a1);
        f32x4 acc = a0 + a1;
#pragma unroll
        for (int r = 0; r < 4; ++r)
          gate_s[myGate][(lane >> 4) * 4 + r][ut * 16 + (lane & 15)] = acc[r];
      }
      asm volatile("s_waitcnt lgkmcnt(0)" ::: "memory");
      if (lane == 0)
        __hip_atomic_fetch_add(&sync_s[0], 1u, __ATOMIC_RELAXED,
                               __HIP_MEMORY_SCOPE_WORKGROUP);
      if (tid < 256) {
        while (__hip_atomic_load(&sync_s[0], __ATOMIC_ACQUIRE,
                                 __HIP_MEMORY_SCOPE_WORKGROUP) < 8u * (unsigned)(t + 1))
          __builtin_amdgcn_s_sleep(1);
        float giA = sigm(gate_s[0][sb][su] + b_i);
        float gfA = sigm(gate_s[1][sb][su] + b_f);
        float ggA = tanhf(gate_s[2][sb][su] + b_g);
        float goA = sigm(gate_s[3][sb][su] + b_o);
        cA = gfA * cA + giA * ggA;
        float hA = goA * tanhf(cA);
        float giB = sigm(gate_s[0][sb + 8][su] + b_i);
        float gfB = sigm(gate_s[1][sb + 8][su] + b_f);
        float ggB = tanhf(gate_s[2][sb + 8][su] + b_g);
        float goB = sigm(gate_s[3][sb + 8][su] + b_o);
        cB = gfB * cB + giB * ggB;
        float hB = goB * tanhf(cB);
        float pA = __shfl_xor(hA, 1);
        float pB = __shfl_xor(hB, 1);
        if (t < SEQ - 1 && (su & 1) == 0) {
          u64 tg = ((u64)(unsigned)(t + 1)) << 32;
          u64 wA = (u64)((uint32_t)f2bf(hA) | ((uint32_t)f2bf(pA) << 16)) | tg;
          u64 wB = (u64)((uint32_t)f2bf(hB) | ((uint32_t)f2bf(pB) << 16)) | tg;
          u64* hbo = hbuf + ((size_t)g * 2 + ((t + 1) & 1)) * 4096;
          const int w = wg * 16 + (su >> 1);
          __hip_atomic_store(hbo + sb * 256 + w, wA,
                             __ATOMIC_RELAXED, __HIP_MEMORY_SCOPE_AGENT);
          __hip_atomic_store(hbo + (sb + 8) * 256 + w, wB,
                             __ATOMIC_RELAXED, __HIP_MEMORY_SCOPE_AGENT);
        }
        o2[((size_t)(bg + sb) * SEQ + t) * HD + u0 + su] = hA;
        o2[((size_t)(bg + sb + 8) * SEQ + t) * HD + u0 + su] = hB;
      }
    }
  } else {
    // ================= COMM =================
    const int ct = tid - 512;
    for (int u = 0; u < SEQ - 1; ++u) {
      const u64* hbin = hbuf + ((size_t)g * 2 + ((u + 1) & 1)) * 4096;
      float xv[5];
      const int xi = ct * 5;
#pragma unroll
      for (int i = 0; i < 5; ++i) {
        int idx = xi + i, r = idx / 40, c = idx % 40;
        xv[i] = x[((size_t)(bg + r) * SEQ + (u + 1)) * DX + c];
      }
      float sv = 0.f;
      if (ct < 16) sv = ssr[(size_t)(bg + ct) * SEQ + (u + 1)];
      u64 v0[16], v1[16];
      const int wa = 2 * ct, wb = 2 * ct + 1;
#pragma unroll
      for (int i = 0; i < 16; ++i) {
        v0[i] = __hip_atomic_load(hbin + i * 256 + wa, __ATOMIC_RELAXED,
                                  __HIP_MEMORY_SCOPE_AGENT);
        v1[i] = __hip_atomic_load(hbin + i * 256 + wb, __ATOMIC_RELAXED,
                                  __HIP_MEMORY_SCOPE_AGENT);
      }
      const unsigned tg = (unsigned)(u + 1);
      for (;;) {
        uint32_t m0 = 0, m1 = 0;
#pragma unroll
        for (int i = 0; i < 16; ++i) {
          m0 |= ((unsigned)(v0[i] >> 32) != tg) ? (1u << i) : 0u;
          m1 |= ((unsigned)(v1[i] >> 32) != tg) ? (1u << i) : 0u;
        }
        if (!(m0 | m1)) break;
        __builtin_amdgcn_s_sleep(1);
#pragma unroll
        for (int i = 0; i < 16; ++i) {
          if (m0 & (1u << i))
            v0[i] = __hip_atomic_load(hbin + i * 256 + wa, __ATOMIC_RELAXED,
                                      __HIP_MEMORY_SCOPE_AGENT);
          if (m1 & (1u << i))
            v1[i] = __hip_atomic_load(hbin + i * 256 + wb, __ATOMIC_RELAXED,
                                      __HIP_MEMORY_SCOPE_AGENT);
        }
      }
      const int np = (u + 1) & 1;
#pragma unroll
      for (int i = 0; i < 16; ++i)
        *(u64*)(&h_s[np][i][ct * 4]) =
            (v0[i] & 0xffffffffull) | (v1[i] << 32);
#pragma unroll
      for (int i = 0; i < 5; ++i) {
        int idx = xi + i, r = idx / 40, c = idx % 40;
        x_s[np][r][c] = f2bf(xv[i]);
      }
      if (ct < 16) x_s[np][ct][40] = f2bf(sv);
      asm volatile("s_waitcnt lgkmcnt(0)" ::: "memory");
      if (lane == 0)
        __hip_atomic_fetch_add(&sync_s[2], 1u, __ATOMIC_RELAXED,
                               __HIP_MEMORY_SCOPE_WORKGROUP);
    }
  }
}

// ---------------- BN-coefficient kernel (1 block) ----------------
__global__ __launch_bounds__(512) void coef_kernel(
    const float* __restrict__ stats, const float* __restrict__ fc1_w,
    const float* __restrict__ fc1_b, const float* __restrict__ fc2_w,
    const float* __restrict__ fc2_b, const float* __restrict__ gamma,
    const float* __restrict__ beta, float* __restrict__ coef)
{
  __shared__ float r1[512], r2[512];
  const int j = threadIdx.x;
  const float inv_n = 1.0f / 32768.0f;
  float mean = stats[j] * inv_n;
  float var = stats[HD + j] * inv_n - mean * mean;
  float scale = gamma[j] * rsqrtf(var + 1e-5f);
  float shift = beta[j] - mean * scale;
  coef[j] = fc1_w[j] * scale;
  coef[HD + j] = fc2_w[j] * scale;
  r1[j] = fc1_w[j] * shift;
  r2[j] = fc2_w[j] * shift;
  __syncthreads();
  for (int s = 256; s > 0; s >>= 1) {
    if (j < s) { r1[j] += r1[j + s]; r2[j] += r2[j + s]; }
    __syncthreads();
  }
  if (j == 0) {
    coef[2 * HD] = r1[0] + fc1_b[0];
    coef[2 * HD + 1] = r2[0] + fc2_b[0];
  }
}

// ---------------- ssr kernel: one wave per (b,t) row ----------------
__global__ __launch_bounds__(256) void ssr_kernel(
    const float* __restrict__ o1, const float* __restrict__ coef,
    float* __restrict__ ssr_ws, float* __restrict__ dssr)
{
  const int row = blockIdx.x * 4 + (threadIdx.x >> 6);
  const int lane = threadIdx.x & 63;
  const float* p = o1 + (size_t)row * HD + lane * 8;
  float s1 = 0.f, s2 = 0.f;
#pragma unroll
  for (int j = 0; j < 8; ++j) {
    float v = p[j];
    s1 += v * coef[lane * 8 + j];
    s2 += v * coef[HD + lane * 8 + j];
  }
#pragma unroll
  for (int off = 32; off > 0; off >>= 1) {
    s1 += __shfl_down(s1, off);
    s2 += __shfl_down(s2, off);
  }
  if (lane == 0) {
    float sr = fmaxf(s1 + coef[2 * HD], 0.0f);
    float w = fabsf(sigm(s2 + coef[2 * HD + 1]));
    float v = sr * (1.0f + w);
    ssr_ws[row] = v;
    dssr[row] = v;
  }
}

// ---------------- fc3 output kernel ----------------
__global__ __launch_bounds__(256) void out_kernel(
    const float* __restrict__ o2, const float* __restrict__ fc3_w,
    const float* __restrict__ fc3_b, float* __restrict__ dout)
{
  const int row = blockIdx.x * 4 + (threadIdx.x >> 6);
  const int lane = threadIdx.x & 63;
  const float* p = o2 + (size_t)row * HD + lane * 8;
  float s = 0.f;
#pragma unroll
  for (int j = 0; j < 8; ++j) s += p[j] * fc3_w[lane * 8 + j];
#pragma unroll
  for (int off = 32; off > 0; off >>= 1) s += __shfl_down(s, off);
  if (lane == 0) dout[row] = fmaxf(s + fc3_b[0], 0.0f);
}

extern "C" void kernel_launch(void* const* d_in, const int* in_sizes, int n_in,
                              void* d_out, int out_size, void* d_ws, size_t ws_size,
                              hipStream_t stream) {
  (void)in_sizes; (void)n_in; (void)out_size; (void)ws_size;
  const float* x    = (const float*)d_in[0];
  const float* gWih = (const float*)d_in[1];
  const float* gWhh = (const float*)d_in[2];
  const float* gbih = (const float*)d_in[3];
  const float* gbhh = (const float*)d_in[4];
  const float* lWih = (const float*)d_in[5];
  const float* lWhh = (const float*)d_in[6];
  const float* lbih = (const float*)d_in[7];
  const float* lbhh = (const float*)d_in[8];
  const float* fc1w = (const float*)d_in[9];
  const float* fc1b = (const float*)d_in[10];
  const float* fc2w = (const float*)d_in[11];
  const float* fc2b = (const float*)d_in[12];
  const float* fc3w = (const float*)d_in[13];
  const float* fc3b = (const float*)d_in[14];
  const float* gam  = (const float*)d_in[15];
  const float* bet  = (const float*)d_in[16];
  float* out = (float*)d_out;

  char* ws = (char*)d_ws;
  float* stats      = (float*)(ws + 16384);           // 1024 f32
  float* coef       = (float*)(ws + 24576);           // 1026 f32
  float* ssr_ws     = (float*)(ws + 32768);           // 32768 f32
  u64* hbuf_g       = (u64*)(ws + 262144);            // 4g x 2par x 32KB
  u64* hbuf_l       = (u64*)(ws + 524288);            // 256KB
  float* o1 = (float*)(ws + 1048576);                 // 64MB
  float* o2 = o1 + (size_t)64 * SEQ * HD;             // 64MB

  hipMemsetAsync(ws + 16384, 0, 4096, stream);        // stats
  hipMemsetAsync(ws + 262144, 0, 524288, stream);     // h exchange (tags=0)

  gru_kernel<<<dim3(64), dim3(640), 0, stream>>>(x, gWih, gWhh, gbih, gbhh,
                                                 hbuf_g, o1, stats);
  coef_kernel<<<dim3(1), dim3(512), 0, stream>>>(stats, fc1w, fc1b, fc2w, fc2b,
                                                 gam, bet, coef);
  ssr_kernel<<<dim3(8192), dim3(256), 0, stream>>>(o1, coef, ssr_ws, out + 32768);
  lstm_kernel<<<dim3(64), dim3(640), 0, stream>>>(x, lWih, lWhh, lbih, lbhh, ssr_ws,
                                                  hbuf_l, o2);
  out_kernel<<<dim3(8192), dim3(256), 0, stream>>>(o2, fc3w, fc3b, out);
}

// Round 7
// 3269.766 us; speedup vs baseline: 2.0687x; 2.0687x over previous
//
#include <hip/hip_runtime.h>
#include <stdint.h>

#define MB 16   // batch rows per group
#define GW 16   // workgroups per group
#define NU 32   // hidden units per WG
#define HD 512
#define SEQ 512
#define DX 40

using short8 = __attribute__((ext_vector_type(8))) short;
using f32x4  = __attribute__((ext_vector_type(4))) float;

__device__ __forceinline__ unsigned short f2bf(float f) {
  uint32_t u = __builtin_bit_cast(uint32_t, f);
  u += 0x7fffu + ((u >> 16) & 1u);
  return (unsigned short)(u >> 16);
}
__device__ __forceinline__ float sigm(float x) { return 1.0f / (1.0f + __expf(-x)); }

#define MFMA_B16(a, b, c) __builtin_amdgcn_mfma_f32_16x16x32_bf16((a), (b), (c), 0, 0, 0)

// R10 = R3 (best measured, 3239us) + two protocol-neutral compute cuts:
//   (1) dual MFMA accumulator chains (dep depth 18 -> 9+1),
//   (2) busy-spin flag poll (no s_sleep quantization).
// h exchange protocol (R3, proven):
//  - h pairs: bf16x2 in 4B words, __hip_atomic_store relaxed AGENT (sc0 sc1,
//    write-through to LLC). __syncthreads drains vmcnt -> data at LLC before
//    the per-WG flag store. No threadfence, no cache invalidates.
//  - fused poll: every staging thread's 4x8B chunks come from ONE producer
//    ((tid&127)>>3), so it polls that producer's flag then loads immediately.
//    16 distinct flag lines only -> wave-coalesced broadcast, tiny traffic.

// ---------------- GRU persistent kernel ----------------
// grid = 64 (4 groups x 16 WGs), 512 threads. Waves 0..5: MFMA (r,z,n x 2 unit
// tiles; n-gate x-fragments are zero). Waves 6,7: xn = x @ Wn^T via 2 MFMAs
// (kept separate because n = tanh(xn + r*hn)).
__global__ __launch_bounds__(512, 2) void gru_kernel(
    const float* __restrict__ x, const float* __restrict__ Wih,
    const float* __restrict__ Whh, const float* __restrict__ bih,
    const float* __restrict__ bhh, unsigned* __restrict__ flags,
    unsigned short* __restrict__ hbuf, float* __restrict__ o1,
    float* __restrict__ stats)
{
  const int wg = blockIdx.x & (GW - 1);
  const int g  = blockIdx.x >> 4;
  const int tid = threadIdx.x;
  const int wave = tid >> 6;
  const int lane = tid & 63;
  const int u0 = wg * NU;
  const int bg = g * MB;

  __shared__ unsigned short h_s[MB][520];  // bf16 h tile
  __shared__ unsigned short x_s[MB][72];   // 0..39 x, 40..63 zero (K-pad)
  __shared__ float gate_s[3][MB][NU];
  __shared__ float xn_s[MB][NU];

  for (int i = tid; i < MB * 32; i += 512) x_s[i >> 5][40 + (i & 31)] = 0;

  // weight B-fragments in registers. B[k][n]: n=lane&15, k=(lane>>4)*8+j.
  short8 bfrag[18];
  const int myGate = wave >> 1;
  const int ut = wave & 1;
  const int kq = (lane >> 4) * 8;
  if (wave < 6) {
    const int row = myGate * HD + u0 + ut * 16 + (lane & 15);
    for (int kt = 0; kt < 16; ++kt) {
      const float* p = Whh + (size_t)row * HD + kt * 32 + kq;
      short8 f;
#pragma unroll
      for (int j = 0; j < 8; ++j) f[j] = (short)f2bf(p[j]);
      bfrag[kt] = f;
    }
    for (int kt = 16; kt < 18; ++kt) {     // x cols: r,z only (n via xn MFMA)
      short8 f;
#pragma unroll
      for (int j = 0; j < 8; ++j) {
        int c = kt * 32 + kq + j - HD;
        float v = (myGate < 2 && c < DX) ? Wih[(size_t)row * DX + c] : 0.0f;
        f[j] = (short)f2bf(v);
      }
      bfrag[kt] = f;
    }
  } else {                                 // waves 6,7: Wn fragments, K=64 pad
    const int row = 2 * HD + u0 + (wave - 6) * 16 + (lane & 15);
    for (int kt = 0; kt < 2; ++kt) {
      short8 f;
#pragma unroll
      for (int j = 0; j < 8; ++j) {
        int c = kt * 32 + kq + j;
        f[j] = (short)((c < DX) ? f2bf(Wih[(size_t)row * DX + c]) : 0);
      }
      bfrag[kt] = f;
    }
  }

  const int sb = tid >> 5;
  const int su = tid & 31;
  float hprev = 0.0f, ssum = 0.0f, ssq = 0.0f;
  const float b_r  = bih[u0 + su] + bhh[u0 + su];
  const float b_z  = bih[HD + u0 + su] + bhh[HD + u0 + su];
  const float b_in = bih[2 * HD + u0 + su];
  const float b_hn = bhh[2 * HD + u0 + su];

  unsigned* gf = flags + g * GW * 16;              // 64B-strided per-WG flags
  unsigned* myProdFlag = gf + ((tid & 127) >> 3) * 16;  // this thread's producer

  for (int t = 0; t < SEQ; ++t) {
    const unsigned long long* hin64 =
        (const unsigned long long*)(hbuf + ((size_t)g * 2 + (t & 1)) * MB * HD);
    uint32_t* hout32 =
        (uint32_t*)(hbuf + ((size_t)g * 2 + ((t + 1) & 1)) * MB * HD);

    {  // fused poll + stage: wait for my producer, then load my 4 chunks
      while (__hip_atomic_load(myProdFlag, __ATOMIC_RELAXED,
                               __HIP_MEMORY_SCOPE_AGENT) < (unsigned)t)
        ;  // busy spin: discovery latency matters more than spin traffic
#pragma unroll
      for (int it = 0; it < 4; ++it) {
        int q = it * 512 + tid;            // 8B-word index into 16KB tile
        unsigned long long v = __hip_atomic_load(hin64 + q, __ATOMIC_RELAXED,
                                                 __HIP_MEMORY_SCOPE_AGENT);
        *(unsigned long long*)(&h_s[q >> 7][(q & 127) * 4]) = v;
      }
    }
    {  // stage x_t
      int b = tid >> 5, c = tid & 31;
      const float* xr = x + ((size_t)(bg + b) * SEQ + t) * DX;
      x_s[b][c] = f2bf(xr[c]);
      if (c < 8) x_s[b][32 + c] = f2bf(xr[32 + c]);
    }
    __syncthreads();  // B: h_s, x_s ready (and all 16 flags >= t block-wide)

    if (wave < 6) {
      const int m = lane & 15;
      f32x4 a0 = {0.f, 0.f, 0.f, 0.f}, a1 = {0.f, 0.f, 0.f, 0.f};
#pragma unroll
      for (int kt = 0; kt < 16; kt += 2) {   // dual chains: halve dep depth
        short8 ha0 = *(const short8*)(&h_s[m][kt * 32 + kq]);
        short8 ha1 = *(const short8*)(&h_s[m][(kt + 1) * 32 + kq]);
        a0 = MFMA_B16(ha0, bfrag[kt], a0);
        a1 = MFMA_B16(ha1, bfrag[kt + 1], a1);
      }
      short8 ax0 = *(const short8*)(&x_s[m][kq]);
      short8 ax1 = *(const short8*)(&x_s[m][32 + kq]);
      a0 = MFMA_B16(ax0, bfrag[16], a0);
      a1 = MFMA_B16(ax1, bfrag[17], a1);
      f32x4 acc = a0 + a1;
#pragma unroll
      for (int r = 0; r < 4; ++r)          // C/D: col=lane&15, row=(lane>>4)*4+r
        gate_s[myGate][(lane >> 4) * 4 + r][ut * 16 + (lane & 15)] = acc[r];
    } else {                               // xn via MFMA, 2 independent chains
      const int m = lane & 15;
      f32x4 c0 = {0.f, 0.f, 0.f, 0.f}, c1 = {0.f, 0.f, 0.f, 0.f};
      short8 ax0 = *(const short8*)(&x_s[m][kq]);
      short8 ax1 = *(const short8*)(&x_s[m][32 + kq]);
      c0 = MFMA_B16(ax0, bfrag[0], c0);
      c1 = MFMA_B16(ax1, bfrag[1], c1);
      f32x4 acc = c0 + c1;
#pragma unroll
      for (int r = 0; r < 4; ++r)
        xn_s[(lane >> 4) * 4 + r][(wave - 6) * 16 + (lane & 15)] = acc[r];
    }
    __syncthreads();  // C: gates + xn ready

    float r_ = sigm(gate_s[0][sb][su] + b_r);
    float z_ = sigm(gate_s[1][sb][su] + b_z);
    float n_ = tanhf(xn_s[sb][su] + b_in + r_ * (gate_s[2][sb][su] + b_hn));
    float h = (1.0f - z_) * n_ + z_ * hprev;
    hprev = h;
    ssum += h; ssq += h * h;
    {  // pack bf16x2 with lane partner, even threads write-through to LLC
      float hp = __shfl_xor(h, 1);
      if ((tid & 1) == 0) {
        uint32_t packed = (uint32_t)f2bf(h) | ((uint32_t)f2bf(hp) << 16);
        __hip_atomic_store(hout32 + ((sb * HD + u0 + su) >> 1), packed,
                           __ATOMIC_RELAXED, __HIP_MEMORY_SCOPE_AGENT);
      }
    }
    __syncthreads();  // D: drains vmcnt -> hout committed at LLC

    if (tid == 0)
      __hip_atomic_store(gf + wg * 16, (unsigned)(t + 1), __ATOMIC_RELAXED,
                         __HIP_MEMORY_SCOPE_AGENT);
    o1[((size_t)(bg + sb) * SEQ + t) * HD + u0 + su] = h;
  }

  atomicAdd(&stats[u0 + su], ssum);
  atomicAdd(&stats[HD + u0 + su], ssq);
}

// ---------------- LSTM persistent kernel ----------------
// 8 MFMA waves (i,f,g,o x 2 unit tiles); x(40)+ssr(1) folded into K-tiles 16,17.
__global__ __launch_bounds__(512, 2) void lstm_kernel(
    const float* __restrict__ x, const float* __restrict__ Wih,
    const float* __restrict__ Whh, const float* __restrict__ bih,
    const float* __restrict__ bhh, const float* __restrict__ ssr,
    unsigned* __restrict__ flags, unsigned short* __restrict__ hbuf,
    float* __restrict__ o2)
{
  const int wg = blockIdx.x & (GW - 1);
  const int g  = blockIdx.x >> 4;
  const int tid = threadIdx.x;
  const int wave = tid >> 6;
  const int lane = tid & 63;
  const int u0 = wg * NU;
  const int bg = g * MB;

  __shared__ unsigned short h_s[MB][520];
  __shared__ unsigned short x_s[MB][72];   // 0..39 x, 40 ssr, 41..63 zero
  __shared__ float gate_s[4][MB][NU];

  for (int i = tid; i < MB * 32; i += 512) x_s[i >> 5][40 + (i & 31)] = 0;

  short8 bfrag[18];
  const int myGate = wave >> 1;
  const int ut = wave & 1;
  const int kq = (lane >> 4) * 8;
  {
    const int row = myGate * HD + u0 + ut * 16 + (lane & 15);
    for (int kt = 0; kt < 16; ++kt) {
      const float* p = Whh + (size_t)row * HD + kt * 32 + kq;
      short8 f;
#pragma unroll
      for (int j = 0; j < 8; ++j) f[j] = (short)f2bf(p[j]);
      bfrag[kt] = f;
    }
    for (int kt = 16; kt < 18; ++kt) {     // Wih has 41 cols (x, ssr)
      short8 f;
#pragma unroll
      for (int j = 0; j < 8; ++j) {
        int c = kt * 32 + kq + j - HD;
        float v = (c < 41) ? Wih[(size_t)row * 41 + c] : 0.0f;
        f[j] = (short)f2bf(v);
      }
      bfrag[kt] = f;
    }
  }

  const int sb = tid >> 5;
  const int su = tid & 31;
  float creg = 0.0f;
  const float b_i = bih[u0 + su] + bhh[u0 + su];
  const float b_f = bih[HD + u0 + su] + bhh[HD + u0 + su];
  const float b_g = bih[2 * HD + u0 + su] + bhh[2 * HD + u0 + su];
  const float b_o = bih[3 * HD + u0 + su] + bhh[3 * HD + u0 + su];

  unsigned* gf = flags + g * GW * 16;
  unsigned* myProdFlag = gf + ((tid & 127) >> 3) * 16;

  for (int t = 0; t < SEQ; ++t) {
    const unsigned long long* hin64 =
        (const unsigned long long*)(hbuf + ((size_t)g * 2 + (t & 1)) * MB * HD);
    uint32_t* hout32 =
        (uint32_t*)(hbuf + ((size_t)g * 2 + ((t + 1) & 1)) * MB * HD);

    {
      while (__hip_atomic_load(myProdFlag, __ATOMIC_RELAXED,
                               __HIP_MEMORY_SCOPE_AGENT) < (unsigned)t)
        ;
#pragma unroll
      for (int it = 0; it < 4; ++it) {
        int q = it * 512 + tid;
        unsigned long long v = __hip_atomic_load(hin64 + q, __ATOMIC_RELAXED,
                                                 __HIP_MEMORY_SCOPE_AGENT);
        *(unsigned long long*)(&h_s[q >> 7][(q & 127) * 4]) = v;
      }
    }
    {
      int b = tid >> 5, c = tid & 31;
      const float* xr = x + ((size_t)(bg + b) * SEQ + t) * DX;
      x_s[b][c] = f2bf(xr[c]);
      if (c < 8) x_s[b][32 + c] = f2bf(xr[32 + c]);
      if (c == 8) x_s[b][40] = f2bf(ssr[(size_t)(bg + b) * SEQ + t]);
    }
    __syncthreads();  // B

    {
      const int m = lane & 15;
      f32x4 a0 = {0.f, 0.f, 0.f, 0.f}, a1 = {0.f, 0.f, 0.f, 0.f};
#pragma unroll
      for (int kt = 0; kt < 16; kt += 2) {   // dual chains
        short8 ha0 = *(const short8*)(&h_s[m][kt * 32 + kq]);
        short8 ha1 = *(const short8*)(&h_s[m][(kt + 1) * 32 + kq]);
        a0 = MFMA_B16(ha0, bfrag[kt], a0);
        a1 = MFMA_B16(ha1, bfrag[kt + 1], a1);
      }
      short8 ax0 = *(const short8*)(&x_s[m][kq]);
      short8 ax1 = *(const short8*)(&x_s[m][32 + kq]);
      a0 = MFMA_B16(ax0, bfrag[16], a0);
      a1 = MFMA_B16(ax1, bfrag[17], a1);
      f32x4 acc = a0 + a1;
#pragma unroll
      for (int r = 0; r < 4; ++r)
        gate_s[myGate][(lane >> 4) * 4 + r][ut * 16 + (lane & 15)] = acc[r];
    }
    __syncthreads();  // C

    float gi = sigm(gate_s[0][sb][su] + b_i);
    float gf_ = sigm(gate_s[1][sb][su] + b_f);
    float gg = tanhf(gate_s[2][sb][su] + b_g);
    float go = sigm(gate_s[3][sb][su] + b_o);
    creg = gf_ * creg + gi * gg;
    float h = go * tanhf(creg);
    {
      float hp = __shfl_xor(h, 1);
      if ((tid & 1) == 0) {
        uint32_t packed = (uint32_t)f2bf(h) | ((uint32_t)f2bf(hp) << 16);
        __hip_atomic_store(hout32 + ((sb * HD + u0 + su) >> 1), packed,
                           __ATOMIC_RELAXED, __HIP_MEMORY_SCOPE_AGENT);
      }
    }
    __syncthreads();  // D

    if (tid == 0)
      __hip_atomic_store(gf + wg * 16, (unsigned)(t + 1), __ATOMIC_RELAXED,
                         __HIP_MEMORY_SCOPE_AGENT);
    o2[((size_t)(bg + sb) * SEQ + t) * HD + u0 + su] = h;
  }
}

// ---------------- BN-coefficient kernel (1 block) ----------------
__global__ __launch_bounds__(512) void coef_kernel(
    const float* __restrict__ stats, const float* __restrict__ fc1_w,
    const float* __restrict__ fc1_b, const float* __restrict__ fc2_w,
    const float* __restrict__ fc2_b, const float* __restrict__ gamma,
    const float* __restrict__ beta, float* __restrict__ coef)
{
  __shared__ float r1[512], r2[512];
  const int j = threadIdx.x;
  const float inv_n = 1.0f / 32768.0f;
  float mean = stats[j] * inv_n;
  float var = stats[HD + j] * inv_n - mean * mean;
  float scale = gamma[j] * rsqrtf(var + 1e-5f);
  float shift = beta[j] - mean * scale;
  coef[j] = fc1_w[j] * scale;
  coef[HD + j] = fc2_w[j] * scale;
  r1[j] = fc1_w[j] * shift;
  r2[j] = fc2_w[j] * shift;
  __syncthreads();
  for (int s = 256; s > 0; s >>= 1) {
    if (j < s) { r1[j] += r1[j + s]; r2[j] += r2[j + s]; }
    __syncthreads();
  }
  if (j == 0) {
    coef[2 * HD] = r1[0] + fc1_b[0];
    coef[2 * HD + 1] = r2[0] + fc2_b[0];
  }
}

// ---------------- ssr kernel: one wave per (b,t) row ----------------
__global__ __launch_bounds__(256) void ssr_kernel(
    const float* __restrict__ o1, const float* __restrict__ coef,
    float* __restrict__ ssr_ws, float* __restrict__ dssr)
{
  const int row = blockIdx.x * 4 + (threadIdx.x >> 6);
  const int lane = threadIdx.x & 63;
  const float* p = o1 + (size_t)row * HD + lane * 8;
  float s1 = 0.f, s2 = 0.f;
#pragma unroll
  for (int j = 0; j < 8; ++j) {
    float v = p[j];
    s1 += v * coef[lane * 8 + j];
    s2 += v * coef[HD + lane * 8 + j];
  }
#pragma unroll
  for (int off = 32; off > 0; off >>= 1) {
    s1 += __shfl_down(s1, off);
    s2 += __shfl_down(s2, off);
  }
  if (lane == 0) {
    float sr = fmaxf(s1 + coef[2 * HD], 0.0f);
    float w = fabsf(sigm(s2 + coef[2 * HD + 1]));
    float v = sr * (1.0f + w);
    ssr_ws[row] = v;
    dssr[row] = v;
  }
}

// ---------------- fc3 output kernel ----------------
__global__ __launch_bounds__(256) void out_kernel(
    const float* __restrict__ o2, const float* __restrict__ fc3_w,
    const float* __restrict__ fc3_b, float* __restrict__ dout)
{
  const int row = blockIdx.x * 4 + (threadIdx.x >> 6);
  const int lane = threadIdx.x & 63;
  const float* p = o2 + (size_t)row * HD + lane * 8;
  float s = 0.f;
#pragma unroll
  for (int j = 0; j < 8; ++j) s += p[j] * fc3_w[lane * 8 + j];
#pragma unroll
  for (int off = 32; off > 0; off >>= 1) s += __shfl_down(s, off);
  if (lane == 0) dout[row] = fmaxf(s + fc3_b[0], 0.0f);
}

extern "C" void kernel_launch(void* const* d_in, const int* in_sizes, int n_in,
                              void* d_out, int out_size, void* d_ws, size_t ws_size,
                              hipStream_t stream) {
  (void)in_sizes; (void)n_in; (void)out_size; (void)ws_size;
  const float* x    = (const float*)d_in[0];
  const float* gWih = (const float*)d_in[1];
  const float* gWhh = (const float*)d_in[2];
  const float* gbih = (const float*)d_in[3];
  const float* gbhh = (const float*)d_in[4];
  const float* lWih = (const float*)d_in[5];
  const float* lWhh = (const float*)d_in[6];
  const float* lbih = (const float*)d_in[7];
  const float* lbhh = (const float*)d_in[8];
  const float* fc1w = (const float*)d_in[9];
  const float* fc1b = (const float*)d_in[10];
  const float* fc2w = (const float*)d_in[11];
  const float* fc2b = (const float*)d_in[12];
  const float* fc3w = (const float*)d_in[13];
  const float* fc3b = (const float*)d_in[14];
  const float* gam  = (const float*)d_in[15];
  const float* bet  = (const float*)d_in[16];
  float* out = (float*)d_out;

  char* ws = (char*)d_ws;
  unsigned* flags_g = (unsigned*)(ws + 0);            // 4 groups x 16 WG x 64B
  unsigned* flags_l = (unsigned*)(ws + 4096);
  float* stats      = (float*)(ws + 8192);            // 1024 f32
  float* coef       = (float*)(ws + 16384);           // 1026 f32
  float* ssr_ws     = (float*)(ws + 32768);           // 32768 f32
  unsigned short* hbuf_g = (unsigned short*)(ws + 262144);   // 128KB
  unsigned short* hbuf_l = (unsigned short*)(ws + 393216);   // 128KB
  float* o1 = (float*)(ws + 1048576);                 // 64MB
  float* o2 = o1 + (size_t)64 * SEQ * HD;             // 64MB

  hipMemsetAsync(ws, 0, 12288, stream);               // flags + stats
  hipMemsetAsync(ws + 262144, 0, 262144, stream);     // h exchange (h0=0)

  gru_kernel<<<dim3(64), dim3(512), 0, stream>>>(x, gWih, gWhh, gbih, gbhh,
                                                 flags_g, hbuf_g, o1, stats);
  coef_kernel<<<dim3(1), dim3(512), 0, stream>>>(stats, fc1w, fc1b, fc2w, fc2b,
                                                 gam, bet, coef);
  ssr_kernel<<<dim3(8192), dim3(256), 0, stream>>>(o1, coef, ssr_ws, out + 32768);
  lstm_kernel<<<dim3(64), dim3(512), 0, stream>>>(x, lWih, lWhh, lbih, lbhh, ssr_ws,
                                                  flags_l, hbuf_l, o2);
  out_kernel<<<dim3(8192), dim3(256), 0, stream>>>(o2, fc3w, fc3b, out);
}